// Round 9
// baseline (194.910 us; speedup 1.0000x reference)
//
#include <hip/hip_runtime.h>

// S4D real: y[l,c] = sum_s w[c,s] * h_s[l],  h_s[l] = x[l,c] + r[c,s]*h_s[l-1]
//
// R14: fused kernel, PER-GROUP tree barriers with store-once release lines.
// Barrier cost model (calibrated on R9+R13): same-line device-scope atomic
// traffic serializes at ~150ns/op at the coherence point. R9 = 1024 pollers
// on one line (170us/barrier). R13 = 512 pollers on the ROOT line -- a line
// concurrently RMW'd by promoters (55us/barrier). Fixes:
//  1. Pollers poll a RELEASE line that receives exactly ONE atomic store.
//  2. Dependency graph decomposes by c-slice: phase-B block bid touches only
//     pids with c-slice bid%8; phase-C (k,cb) reads only writers == cb mod 8.
//     => 8 INDEPENDENT groups of 64 blocks; barrier spans 64, groups skew
//     freely. Arrival: 8 shards x 8 RMW; promote: 8 RMW; release: 1 store;
//     detect: 64 pure loads on a quiet line. ~4us/barrier predicted.
// Residency: 512 blocks @ __launch_bounds__(256,2) (68 VGPR, 9KB LDS) -> all
// co-resident (PROVEN: R13's barriers released). Bounded spin ~6ms worst case
// -> wrong answer, never a hang. Phase bodies verbatim from R12/R13 (passed).

namespace {

constexpr int L_ = 4096;
constexpr int CH_ = 512;
constexpr int S_ = 64;
constexpr float DT = 1.0f / 4096.0f;
constexpr int SC = S_ * CH_;   // 32768 (s,c) pairs
constexpr int SG = 16;         // states per thread (S_ / 4 waves)
constexpr int T_ = 64;         // chunk length
constexpr int NC_ = L_ / T_;   // 64 chunks
constexpr int GJ = 16;         // chunks per combine thread (4 waves x 16 = 64)
constexpr int NB = NC_ * 8;    // 512 blocks

// Counter layout: per (phase, group): 16 slots x 64 u32 (256B-spaced lines).
// slots 0..7 arrival shards, 8 root, 9 release. 2 phases x 8 groups.
constexpr int SLOT_U32 = 64;
constexpr int SLOTS_PG = 16;
constexpr int CTR_U32 = 2 * 8 * SLOTS_PG * SLOT_U32;  // 16384 u32 = 64 KB

__device__ __forceinline__ void group_barrier(unsigned* __restrict__ ctr,
                                              int phase, int group, int q) {
  unsigned* base = ctr + (size_t)((phase * 8 + group) * SLOTS_PG) * SLOT_U32;
  unsigned* sh = base + (size_t)(q & 7) * SLOT_U32;  // arrival shard
  unsigned* rt = base + 8 * SLOT_U32;                // promotion root
  unsigned* rl = base + 9 * SLOT_U32;                // release (ONE store)
  __syncthreads();
  if (threadIdx.x == 0) {
    __threadfence();  // publish this block's global writes
    const unsigned t = __hip_atomic_fetch_add(sh, 1u, __ATOMIC_ACQ_REL,
                                              __HIP_MEMORY_SCOPE_AGENT);
    if (t == 7u) {  // shard-last of 8 arrivals
      const unsigned u = __hip_atomic_fetch_add(rt, 1u, __ATOMIC_ACQ_REL,
                                                __HIP_MEMORY_SCOPE_AGENT);
      if (u == 7u)  // group-last shard
        __hip_atomic_store(rl, 1u, __ATOMIC_RELEASE, __HIP_MEMORY_SCOPE_AGENT);
    }
    // Bounded poll (~6ms max): wrong answer beats a hang. Release line gets
    // only pure loads after its single store -> cheap detection.
    for (int it = 0; it < 30000; ++it) {
      if (__hip_atomic_load(rl, __ATOMIC_ACQUIRE, __HIP_MEMORY_SCOPE_AGENT))
        break;
      __builtin_amdgcn_s_sleep(8);  // ~512 cy between polls
    }
    __threadfence();  // import group peers' writes
  }
  __syncthreads();
}

// Compute r (and optionally w) for states [s0, s0+16) of channel c.
__device__ __forceinline__ void params16(const float* __restrict__ la,
                                         const float* __restrict__ Bg,
                                         const float* __restrict__ Cg,
                                         int c, int s0, float* r, float* w) {
  const float4* lap = reinterpret_cast<const float4*>(la + c * S_ + s0);
  if (w == nullptr) {
#pragma unroll
    for (int q = 0; q < 4; ++q) {
      const float4 v = lap[q];
      const float a[4] = {v.x, v.y, v.z, v.w};
#pragma unroll
      for (int t = 0; t < 4; ++t) {
        const float A = -expf(a[t]);
        r[q * 4 + t] = expf(A * DT);
      }
    }
  } else {
    const float4* bp = reinterpret_cast<const float4*>(Bg + c * S_ + s0);
    const float4* cp = reinterpret_cast<const float4*>(Cg + c * S_ + s0);
#pragma unroll
    for (int q = 0; q < 4; ++q) {
      const float4 v = lap[q], bb = bp[q], cc = cp[q];
      const float a[4] = {v.x, v.y, v.z, v.w};
      const float bv[4] = {bb.x, bb.y, bb.z, bb.w};
      const float cv[4] = {cc.x, cc.y, cc.z, cc.w};
#pragma unroll
      for (int t = 0; t < 4; ++t) {
        const float A = -expf(a[t]);
        const float rr = expf(A * DT);
        r[q * 4 + t] = rr;
        w[q * 4 + t] = cv[t] * ((rr - 1.0f) * bv[t] / A);
      }
    }
  }
}

// ---------------------------------------------------------------------------
__global__ __launch_bounds__(256, 2)
void s4d_one(const float* __restrict__ x, const float* __restrict__ la,
             const float* __restrict__ Bg, const float* __restrict__ Cg,
             float* __restrict__ carry,   // [NC_][SC] = 8 MB
             unsigned* __restrict__ ctr,  // barrier counters (memset to 0)
             float* __restrict__ y) {
  __shared__ float lds[4][8][64];  // phase C reduce (8 KB)
  __shared__ float aggs[4][64];    // phase B group prefix (1 KB)

  const int tid = threadIdx.x;
  const int bid = blockIdx.x;
  const int lane = tid & 63;
  const int g = tid >> 6;          // wave id
  const int k = bid >> 3;          // chunk (also within-group index q)
  const int cb = (bid & 7) << 6;   // channel-block base
  const int grp = bid & 7;         // barrier group = c-slice
  const int c = cb + lane;
  const int s0 = g * SG;

  // ---------------- Phase A: local chunk scan -> chunk-end states -----------
  {
    const float* xp = x + (size_t)k * T_ * CH_ + c;
    float xb[16];
#pragma unroll
    for (int j = 0; j < 16; ++j) xb[j] = xp[j * CH_];  // issue before expf

    float r[SG], h[SG];
    params16(la, nullptr, nullptr, c, s0, r, nullptr);
#pragma unroll
    for (int i = 0; i < SG; ++i) h[i] = 0.0f;

    for (int l0 = 0; l0 < T_; l0 += 16) {
      float xc[16];
#pragma unroll
      for (int j = 0; j < 16; ++j) xc[j] = xb[j];
      const int ln = (l0 + 16 < T_) ? l0 + 16 : l0;  // branchless tail
#pragma unroll
      for (int j = 0; j < 16; ++j) xb[j] = xp[(ln + j) * CH_];
#pragma unroll
      for (int j = 0; j < 16; ++j) {
        const float xv = xc[j];
#pragma unroll
        for (int i = 0; i < SG; ++i) h[i] = fmaf(r[i], h[i], xv);
      }
    }

    float* ew = carry + (size_t)k * SC + s0 * CH_ + c;
#pragma unroll
    for (int i = 0; i < SG; ++i) ew[i * CH_] = h[i];
  }

  group_barrier(ctr, 0, grp, k);

  // ---------------- Phase B: chunk ends -> chunk carry-ins (in place) -------
  // Re-identity: block = 64 pids x 4 waves; wave j owns chunks [16j, 16j+16).
  // pid c-slice == bid%8 (index algebra) -> stays inside this barrier group.
  {
    const int p = tid & 63;
    const int j = g;                        // 0..3, wave-uniform
    const int pid = (bid << 6) + p;         // s*CH + c
    const int s = pid >> 9;
    const int c2 = pid & (CH_ - 1);

    float v[GJ];
#pragma unroll
    for (int m = 0; m < GJ; ++m) v[m] = carry[(size_t)(j * GJ + m) * SC + pid];

    const float A = -expf(la[c2 * S_ + s]);
    const float rT = expf(A * (DT * (float)T_));  // r^T
    float rTG = rT;                                // -> rT^16 (4 squarings)
    rTG *= rTG; rTG *= rTG; rTG *= rTG; rTG *= rTG;

    float agg = 0.0f;
#pragma unroll
    for (int m = 0; m < GJ; ++m) agg = fmaf(rT, agg, v[m]);
    aggs[j][p] = agg;
    __syncthreads();

    float G = 0.0f;  // carry-in of group j
    for (int j2 = 0; j2 < j; ++j2) G = fmaf(rTG, G, aggs[j2][p]);

    float st = G;
#pragma unroll
    for (int m = 0; m < GJ; ++m) {
      carry[(size_t)(j * GJ + m) * SC + pid] = st;  // carry-IN of chunk
      st = fmaf(rT, st, v[m]);
    }
  }

  group_barrier(ctr, 1, grp, k);

  // ---------------- Phase C: seeded re-scan + output ------------------------
  {
    float h[SG];
    const float* crd = carry + (size_t)k * SC + s0 * CH_ + c;
#pragma unroll
    for (int i = 0; i < SG; ++i) h[i] = crd[i * CH_];  // issue early

    const float* xp = x + (size_t)k * T_ * CH_ + c;
    float xb[8];
#pragma unroll
    for (int j = 0; j < 8; ++j) xb[j] = xp[j * CH_];   // issue early

    float r[SG], w[SG];
    params16(la, Bg, Cg, c, s0, r, w);

    float* yp = y + (size_t)k * T_ * CH_;

    for (int l = 0; l < T_; l += 8) {
      float xc[8];
#pragma unroll
      for (int j = 0; j < 8; ++j) xc[j] = xb[j];
      const int ln = (l + 8 < T_) ? l + 8 : l;  // branchless tail
#pragma unroll
      for (int j = 0; j < 8; ++j) xb[j] = xp[(ln + j) * CH_];

      float part[8];
#pragma unroll
      for (int jj = 0; jj < 8; ++jj) {
        const float xv = xc[jj];
        float a0 = 0, a1 = 0, a2 = 0, a3 = 0;
#pragma unroll
        for (int i = 0; i < SG; i += 4) {
          h[i]     = fmaf(r[i],     h[i],     xv);
          h[i + 1] = fmaf(r[i + 1], h[i + 1], xv);
          h[i + 2] = fmaf(r[i + 2], h[i + 2], xv);
          h[i + 3] = fmaf(r[i + 3], h[i + 3], xv);
          a0 = fmaf(w[i],     h[i],     a0);
          a1 = fmaf(w[i + 1], h[i + 1], a1);
          a2 = fmaf(w[i + 2], h[i + 2], a2);
          a3 = fmaf(w[i + 3], h[i + 3], a3);
        }
        part[jj] = (a0 + a1) + (a2 + a3);
      }

#pragma unroll
      for (int jj = 0; jj < 8; ++jj) lds[g][jj][lane] = part[jj];
      __syncthreads();
#pragma unroll
      for (int p = 0; p < 2; ++p) {
        const int idx = tid + p * 256;
        const int jj = idx >> 6;
        const int ln2 = idx & 63;
        const float vv = (lds[0][jj][ln2] + lds[1][jj][ln2]) +
                         (lds[2][jj][ln2] + lds[3][jj][ln2]);
        yp[(size_t)(l + jj) * CH_ + cb + ln2] = vv;
      }
      __syncthreads();
    }
  }
}

// ---------------- Degenerate fallback: full-length serial scan --------------
__global__ __launch_bounds__(256) void k_scan_full(const float* __restrict__ x,
                                                   const float* __restrict__ la,
                                                   const float* __restrict__ Bg,
                                                   const float* __restrict__ Cg,
                                                   float* __restrict__ y) {
  __shared__ float lds[4][8][64];
  const int lane = threadIdx.x & 63;
  const int g = threadIdx.x >> 6;
  const int cb = (blockIdx.x & 7) << 6;
  const int c = cb + lane;
  const int s0 = g * SG;

  float r[SG], w[SG], h[SG];
  params16(la, Bg, Cg, c, s0, r, w);
#pragma unroll
  for (int i = 0; i < SG; ++i) h[i] = 0.0f;

  const float* xp = x + c;
  float* yp = y;

  for (int l = 0; l < L_; l += 8) {
    float part[8];
#pragma unroll
    for (int jj = 0; jj < 8; ++jj) {
      const float xv = xp[(size_t)(l + jj) * CH_];
      float a0 = 0, a1 = 0, a2 = 0, a3 = 0;
#pragma unroll
      for (int i = 0; i < SG; i += 4) {
        h[i]     = fmaf(r[i],     h[i],     xv);
        h[i + 1] = fmaf(r[i + 1], h[i + 1], xv);
        h[i + 2] = fmaf(r[i + 2], h[i + 2], xv);
        h[i + 3] = fmaf(r[i + 3], h[i + 3], xv);
        a0 = fmaf(w[i],     h[i],     a0);
        a1 = fmaf(w[i + 1], h[i + 1], a1);
        a2 = fmaf(w[i + 2], h[i + 2], a2);
        a3 = fmaf(w[i + 3], h[i + 3], a3);
      }
      part[jj] = (a0 + a1) + (a2 + a3);
    }
#pragma unroll
    for (int jj = 0; jj < 8; ++jj) lds[g][jj][lane] = part[jj];
    __syncthreads();
#pragma unroll
    for (int p = 0; p < 2; ++p) {
      const int idx = (int)threadIdx.x + p * 256;
      const int jj = idx >> 6;
      const int ln = idx & 63;
      const float vv = (lds[0][jj][ln] + lds[1][jj][ln]) +
                       (lds[2][jj][ln] + lds[3][jj][ln]);
      yp[(size_t)(l + jj) * CH_ + cb + ln] = vv;
    }
    __syncthreads();
  }
}

}  // namespace

extern "C" void kernel_launch(void* const* d_in, const int* in_sizes, int n_in,
                              void* d_out, int out_size, void* d_ws, size_t ws_size,
                              hipStream_t stream) {
  const float* x = (const float*)d_in[0];
  const float* la = (const float*)d_in[1];
  const float* B = (const float*)d_in[2];
  const float* C = (const float*)d_in[3];
  float* y = (float*)d_out;
  float* ws = (float*)d_ws;

  const size_t carry_f = (size_t)NC_ * SC;  // 8 MB
  const size_t need = carry_f * sizeof(float) + CTR_U32 * sizeof(unsigned);
  if (ws_size >= need) {
    float* carry = ws;
    unsigned* ctr = (unsigned*)(ws + carry_f);
    hipMemsetAsync((void*)ctr, 0, CTR_U32 * sizeof(unsigned), stream);
    s4d_one<<<NB, 256, 0, stream>>>(x, la, B, C, carry, ctr, y);
  } else {
    k_scan_full<<<8, 256, 0, stream>>>(x, la, B, C, y);
  }
}

// Round 10
// 89.949 us; speedup vs baseline: 2.1669x; 2.1669x over previous
//
#include <hip/hip_runtime.h>

// S4D real: y[l,c] = sum_s w[c,s] * h_s[l],  h_s[l] = x[l,c] + r[c,s]*h_s[l-1]
//
// R15 = R12 verbatim (best measured: 90.7us). Pre-committed stop rule from
// R14 fired: every fusion/barrier variant (R9/R13/R14: 584/186/195us) loses
// to the 3-dispatch structure because grid-wide sync on this 8-XCD part
// costs >=40us/barrier at the L3 coherence point (insensitive to polling
// topology, R13 vs R14), while the dispatch boundaries it replaces cost
// only ~20us total. Structural ledger (10 variants) in session notes.
// Window model: dur ~= 42us harness poison-fill (BW-bound, untouchable)
// + ~46us kernels+boundaries (vs ~11us pure VALU+HBM floor; gap is
// per-dispatch ramp/drain, measured at ~8-10us/node in this harness).
//   K1 k_local : per-chunk scan (T=64), zero carry-in -> chunk ends E
//                (16-deep x prefetch, loads issued before expf chain)
//   K2 k_comb  : E -> per-chunk carry-INs in place (4 waves x 16 chunks,
//                LDS group prefix; loads-first)
//   K3 k_scan  : seeded re-scan + y = sum_s w*h (8-deep prefetch,
//                LDS cross-wave reduce)

namespace {

constexpr int L_ = 4096;
constexpr int CH_ = 512;
constexpr int S_ = 64;
constexpr float DT = 1.0f / 4096.0f;
constexpr int SC = S_ * CH_;   // 32768 (s,c) pairs
constexpr int SG = 16;         // states per thread (S_ / 4 waves)
constexpr int T_ = 64;         // chunk length
constexpr int NC_ = L_ / T_;   // 64 chunks
constexpr int GJ = 16;         // chunks per combine thread
constexpr int NJ = NC_ / GJ;   // 4 combine groups per (s,c) = waves/block

// Compute r (and optionally w) for states [s0, s0+16) of channel c.
__device__ __forceinline__ void params16(const float* __restrict__ la,
                                         const float* __restrict__ Bg,
                                         const float* __restrict__ Cg,
                                         int c, int s0, float* r, float* w) {
  const float4* lap = reinterpret_cast<const float4*>(la + c * S_ + s0);
  if (w == nullptr) {
#pragma unroll
    for (int q = 0; q < 4; ++q) {
      const float4 v = lap[q];
      const float a[4] = {v.x, v.y, v.z, v.w};
#pragma unroll
      for (int t = 0; t < 4; ++t) {
        const float A = -expf(a[t]);
        r[q * 4 + t] = expf(A * DT);
      }
    }
  } else {
    const float4* bp = reinterpret_cast<const float4*>(Bg + c * S_ + s0);
    const float4* cp = reinterpret_cast<const float4*>(Cg + c * S_ + s0);
#pragma unroll
    for (int q = 0; q < 4; ++q) {
      const float4 v = lap[q], bb = bp[q], cc = cp[q];
      const float a[4] = {v.x, v.y, v.z, v.w};
      const float bv[4] = {bb.x, bb.y, bb.z, bb.w};
      const float cv[4] = {cc.x, cc.y, cc.z, cc.w};
#pragma unroll
      for (int t = 0; t < 4; ++t) {
        const float A = -expf(a[t]);
        const float rr = expf(A * DT);
        r[q * 4 + t] = rr;
        w[q * 4 + t] = cv[t] * ((rr - 1.0f) * bv[t] / A);
      }
    }
  }
}

// ---------------- K1: local chunk-end states (zero carry-in) ----------------
// grid = NC_*8 = 512 blocks, 256 thr. wave g: states [16g,16g+16), lane: c.
__global__ __launch_bounds__(256)
void k_local(const float* __restrict__ x, const float* __restrict__ la,
             float* __restrict__ E) {
  const int lane = threadIdx.x & 63;
  const int g = threadIdx.x >> 6;
  const int k = blockIdx.x >> 3;
  const int c = ((blockIdx.x & 7) << 6) + lane;
  const int s0 = g * SG;

  // Issue the first 16 x loads BEFORE the expf chain (overlap ~900cy HBM).
  const float* xp = x + (size_t)k * T_ * CH_ + c;
  float xb[16];
#pragma unroll
  for (int j = 0; j < 16; ++j) xb[j] = xp[j * CH_];

  float r[SG], h[SG];
  params16(la, nullptr, nullptr, c, s0, r, nullptr);
#pragma unroll
  for (int i = 0; i < SG; ++i) h[i] = 0.0f;

  for (int l0 = 0; l0 < T_; l0 += 16) {
    float xc[16];
#pragma unroll
    for (int j = 0; j < 16; ++j) xc[j] = xb[j];
    const int ln = (l0 + 16 < T_) ? l0 + 16 : l0;  // branchless tail re-load
#pragma unroll
    for (int j = 0; j < 16; ++j) xb[j] = xp[(ln + j) * CH_];
#pragma unroll
    for (int j = 0; j < 16; ++j) {
      const float xv = xc[j];
#pragma unroll
      for (int i = 0; i < SG; ++i) h[i] = fmaf(r[i], h[i], xv);
    }
  }

  float* ew = E + (size_t)k * SC + s0 * CH_ + c;
#pragma unroll
  for (int i = 0; i < SG; ++i) ew[i * CH_] = h[i];
}

// ---------------- K2: chunk ends -> chunk carry-ins (in place) --------------
// Block: 64 pids x NJ waves (wave j owns chunks [GJ*j, GJ*j+GJ)).
__global__ __launch_bounds__(256)
void k_comb(const float* __restrict__ la, float* __restrict__ carry) {
  __shared__ float aggs[NJ][64];
  const int p = threadIdx.x & 63;
  const int j = threadIdx.x >> 6;            // 0..NJ-1, wave-uniform
  const int pid = (blockIdx.x << 6) + p;     // s*CH + c
  const int s = pid >> 9;
  const int c = pid & (CH_ - 1);

  // Loads first: 16 coalesced 256B/wave reads in flight before any VALU.
  float v[GJ];
#pragma unroll
  for (int m = 0; m < GJ; ++m) v[m] = carry[(size_t)(j * GJ + m) * SC + pid];

  const float A = -expf(la[c * S_ + s]);
  const float rT = expf(A * (DT * (float)T_));  // r^T
  float rTG = rT;                                // -> rT^GJ (4 squarings)
  rTG *= rTG;  // ^2
  rTG *= rTG;  // ^4
  rTG *= rTG;  // ^8
  rTG *= rTG;  // ^16

  float agg = 0.0f;
#pragma unroll
  for (int m = 0; m < GJ; ++m) agg = fmaf(rT, agg, v[m]);
  aggs[j][p] = agg;
  __syncthreads();

  float G = 0.0f;  // carry-in of group j
  for (int j2 = 0; j2 < j; ++j2) G = fmaf(rTG, G, aggs[j2][p]);

  float st = G;
#pragma unroll
  for (int m = 0; m < GJ; ++m) {
    carry[(size_t)(j * GJ + m) * SC + pid] = st;  // carry-IN of chunk GJ*j+m
    st = fmaf(rT, st, v[m]);
  }
}

// ---------------- K3: seeded re-scan + output -------------------------------
template <int T, bool USE_CARRY>
__global__ __launch_bounds__(256)
void k_scan(const float* __restrict__ x, const float* __restrict__ la,
            const float* __restrict__ Bg, const float* __restrict__ Cg,
            const float* __restrict__ carry, float* __restrict__ y) {
  __shared__ float lds[4][8][64];  // [s-group][l-row][lane]

  const int lane = threadIdx.x & 63;
  const int g = threadIdx.x >> 6;
  const int k = blockIdx.x >> 3;
  const int cb = (blockIdx.x & 7) << 6;
  const int c = cb + lane;
  const int s0 = g * SG;

  // Issue E row + first 8 x loads BEFORE the param expf/div chain.
  float h[SG];
  if (USE_CARRY) {
    const float* crd = carry + (size_t)k * SC + s0 * CH_ + c;
#pragma unroll
    for (int i = 0; i < SG; ++i) h[i] = crd[i * CH_];
  } else {
#pragma unroll
    for (int i = 0; i < SG; ++i) h[i] = 0.0f;
  }
  const float* xp = x + (size_t)k * T * CH_ + c;
  float xb[8];
#pragma unroll
  for (int j = 0; j < 8; ++j) xb[j] = xp[j * CH_];

  float r[SG], w[SG];
  params16(la, Bg, Cg, c, s0, r, w);

  float* yp = y + (size_t)k * T * CH_;

  for (int l = 0; l < T; l += 8) {
    float xc[8];
#pragma unroll
    for (int j = 0; j < 8; ++j) xc[j] = xb[j];
    const int ln = (l + 8 < T) ? l + 8 : l;  // branchless tail re-load
#pragma unroll
    for (int j = 0; j < 8; ++j) xb[j] = xp[(ln + j) * CH_];

    float part[8];
#pragma unroll
    for (int jj = 0; jj < 8; ++jj) {
      const float xv = xc[jj];
      float a0 = 0, a1 = 0, a2 = 0, a3 = 0;
#pragma unroll
      for (int i = 0; i < SG; i += 4) {
        h[i]     = fmaf(r[i],     h[i],     xv);
        h[i + 1] = fmaf(r[i + 1], h[i + 1], xv);
        h[i + 2] = fmaf(r[i + 2], h[i + 2], xv);
        h[i + 3] = fmaf(r[i + 3], h[i + 3], xv);
        a0 = fmaf(w[i],     h[i],     a0);
        a1 = fmaf(w[i + 1], h[i + 1], a1);
        a2 = fmaf(w[i + 2], h[i + 2], a2);
        a3 = fmaf(w[i + 3], h[i + 3], a3);
      }
      part[jj] = (a0 + a1) + (a2 + a3);
    }

#pragma unroll
    for (int jj = 0; jj < 8; ++jj) lds[g][jj][lane] = part[jj];
    __syncthreads();
#pragma unroll
    for (int p = 0; p < 2; ++p) {
      const int idx = (int)threadIdx.x + p * 256;
      const int jj = idx >> 6;
      const int ln2 = idx & 63;
      const float vv = (lds[0][jj][ln2] + lds[1][jj][ln2]) +
                       (lds[2][jj][ln2] + lds[3][jj][ln2]);
      yp[(size_t)(l + jj) * CH_ + cb + ln2] = vv;
    }
    __syncthreads();
  }
}

}  // namespace

extern "C" void kernel_launch(void* const* d_in, const int* in_sizes, int n_in,
                              void* d_out, int out_size, void* d_ws, size_t ws_size,
                              hipStream_t stream) {
  const float* x = (const float*)d_in[0];
  const float* la = (const float*)d_in[1];
  const float* B = (const float*)d_in[2];
  const float* C = (const float*)d_in[3];
  float* y = (float*)d_out;
  float* E = (float*)d_ws;

  const size_t need = (size_t)NC_ * SC * sizeof(float);  // 8 MB
  if (ws_size >= need) {
    k_local<<<NC_ * 8, 256, 0, stream>>>(x, la, E);
    k_comb<<<SC / 64, 256, 0, stream>>>(la, E);
    k_scan<T_, true><<<NC_ * 8, 256, 0, stream>>>(x, la, B, C, E, y);
  } else {
    k_scan<L_, false><<<8, 256, 0, stream>>>(x, la, B, C, nullptr, y);
  }
}